// Round 5
// baseline (305.199 us; speedup 1.0000x reference)
//
#include <hip/hip_runtime.h>

#define B_ 4
#define C_ 128
#define H_ 256
#define W_ 256
#define CQK 16
#define NPOOL 4096   // (256/4)*(256/4)
#define KSPLIT 2

typedef short bf16x8 __attribute__((ext_vector_type(8)));     // 8 bf16 (4 VGPRs)
typedef float f32x4 __attribute__((ext_vector_type(4)));
typedef float f32x2 __attribute__((ext_vector_type(2)));
typedef unsigned short ushort8 __attribute__((ext_vector_type(8)));

__device__ __forceinline__ unsigned short f2bf(float f) {
    unsigned int u = __float_as_uint(f);
    unsigned int r = (u + 0x7fffu + ((u >> 16) & 1u)) >> 16;  // RNE
    return (unsigned short)r;
}

// ---------------------------------------------------------------------------
// K1-fast (gamma==0 only): q/k conv + pool + fused out=x copy.
// Block = one pooled row (4h x 256w = 1024 px), 512 threads, ALL 32 outputs
// -> x read exactly once, as 4KB-contiguous per-channel streams (vs 256B
// scattered segments before). Weights staged once in LDS (16KB). x chunks
// (8 c) staged via register prefetch (2-barrier m97 pattern); out=x stored
// from the same registers. LDS x layout pair-transposed so compute ds_read_b64
// is 2-way (free); pool reduction padded (stride 33) to avoid 64-way writes.
// Thread decomposition: t = wh*256 + hl*64 + pw; acc[o=32][e=2] covers
// pixel (h=ph*4+hl, w=pw*4+wh*2+e).
// ---------------------------------------------------------------------------
__global__ __launch_bounds__(512) void qk_fast_k(
    const float* __restrict__ x,
    const float* __restrict__ wq, const float* __restrict__ bq,
    const float* __restrict__ wk, const float* __restrict__ bk,
    const float* __restrict__ gamma,
    float* __restrict__ qpT, float* __restrict__ kp,
    float* __restrict__ out)
{
    if (gamma[0] != 0.0f) return;       // general path handled by qkv_pool_k

    const int bx = blockIdx.x;
    const int b  = bx >> 6;
    const int ph = bx & 63;
    const int t  = threadIdx.x;

    __shared__ float big[8 * 64 * 33];  // 67.6KB: staging (32KB) then reduction
    __shared__ float wlds[C_ * 32];     // 16KB: w[c][o], o: q0..15,k0..15

    // ---- stage all weights once: idx -> (o = idx>>7, c = idx&127), coalesced
    #pragma unroll
    for (int q = 0; q < 8; ++q) {
        const int idx = t + q*512;
        const int o = idx >> 7, c = idx & 127;
        wlds[c*32 + o] = (o < 16) ? wq[o*C_ + c] : wk[(o-16)*C_ + c];
    }

    const int pw = t & 63;
    const int hl = (t >> 6) & 3;
    const int wh = t >> 8;              // 0..1

    float acc[32][2];
    #pragma unroll
    for (int o = 0; o < 32; ++o) { acc[o][0] = 0.f; acc[o][1] = 0.f; }

    // staging decomposition: idx = t + q*512 (q=0..3) -> cl = idx>>8, fo = idx&255
    const int s_cl = t >> 8;            // base cl contribution handled via q
    (void)s_cl;

    const f32x4* x4 = (const f32x4*)x;
    f32x4*       o4 = (f32x4*)out;

    f32x4 pre[4];
    size_t g4[4];
    {   // prologue: issue loads for chunk 0
        #pragma unroll
        for (int q = 0; q < 4; ++q) {
            const int idx = t + q*512;
            const int cl = idx >> 8, fo = idx & 255;
            g4[q] = (size_t)(b*C_ + 0 + cl)*(H_*W_/4) + ph*(W_) + fo; // (H_*W_/4)=16384, ph*4 rows /4*W_... = ph*1024/4*4
            // float4 index: ((b*C_+cl)*H_ + ph*4)*W_/4 + fo = (b*C_+cl)*16384 + ph*256 + fo
            g4[q] = (size_t)(b*C_ + cl)*16384 + ph*256 + fo;
            pre[q] = x4[g4[q]];
        }
    }

    for (int c0 = 0; c0 < C_; c0 += 8) {
        __syncthreads();                // big[] safe to overwrite
        // write staged chunk to LDS (pair-transposed) + fused out=x store
        #pragma unroll
        for (int q = 0; q < 4; ++q) {
            const int idx = t + q*512;
            const int cl = idx >> 8, fo = idx & 255;
            const int rhl = fo >> 6, pwf = fo & 63;
            const f32x4 v = pre[q];
            o4[g4[q]] = v;
            // pairs: (wh=0 -> v.xy), (wh=1 -> v.zw); pair offset ((wh*4+hl)*64+pw)*2
            float* base = &big[cl*1024];
            *(f32x2*)&base[((0*4 + rhl)*64 + pwf)*2] = (f32x2){v[0], v[1]};
            *(f32x2*)&base[((1*4 + rhl)*64 + pwf)*2] = (f32x2){v[2], v[3]};
        }
        __syncthreads();                // staged data visible
        // issue next chunk's loads (independent of compute below)
        if (c0 + 8 < C_) {
            #pragma unroll
            for (int q = 0; q < 4; ++q) {
                const int idx = t + q*512;
                const int cl = idx >> 8, fo = idx & 255;
                g4[q] = (size_t)(b*C_ + c0 + 8 + cl)*16384 + ph*256 + fo;
                pre[q] = x4[g4[q]];
            }
        }
        // compute 8 channels
        #pragma unroll
        for (int cl = 0; cl < 8; ++cl) {
            const int c = c0 + cl;
            const f32x2 xv = *(const f32x2*)&big[cl*1024 + ((wh*4 + hl)*64 + pw)*2];
            const float* wrow = &wlds[c*32];
            #pragma unroll
            for (int og = 0; og < 8; ++og) {
                const f32x4 w4 = *(const f32x4*)&wrow[og*4];
                #pragma unroll
                for (int j = 0; j < 4; ++j) {
                    acc[og*4+j][0] = fmaf(w4[j], xv[0], acc[og*4+j][0]);
                    acc[og*4+j][1] = fmaf(w4[j], xv[1], acc[og*4+j][1]);
                }
            }
        }
    }

    // ---- pool: thread-local over e, then LDS over 8 waves (hl x wh)
    __syncthreads();                    // done with staging area
    const int wv = t >> 6;              // 0..7
    #pragma unroll
    for (int o = 0; o < 32; ++o) {
        big[(wv*64 + pw)*33 + o] = fmaxf(acc[o][0], acc[o][1]);
    }
    __syncthreads();

    const int n0 = ph*64;
    #pragma unroll
    for (int q = 0; q < 4; ++q) {
        const int p  = t + q*512;       // 0..2047 = (pw2, o)
        const int o  = p & 31;
        const int p2 = (p >> 5) & 63;
        float val = big[(0*64 + p2)*33 + o];
        #pragma unroll
        for (int w8 = 1; w8 < 8; ++w8)
            val = fmaxf(val, big[(w8*64 + p2)*33 + o]);
        const int n = n0 + p2;
        if (o < 16) { val += bq[o];    qpT[((size_t)b*NPOOL + n)*CQK + o] = val; }
        else        { val += bk[o-16]; kp[(b*CQK + (o-16))*NPOOL + n] = val; }
    }
}

// ---------------------------------------------------------------------------
// K1-general (gamma!=0 only): original fused qkv conv + pool.
// ---------------------------------------------------------------------------
__global__ __launch_bounds__(256) void qkv_pool_k(
    const float* __restrict__ x,
    const float* __restrict__ wq, const float* __restrict__ bq,
    const float* __restrict__ wk, const float* __restrict__ bk,
    const float* __restrict__ wv, const float* __restrict__ bv,
    const float* __restrict__ gamma,
    float* __restrict__ qpT, float* __restrict__ kp,
    unsigned short* __restrict__ vbf)
{
    if (gamma[0] == 0.0f) return;       // fast path handled by qk_fast_k

    const int og = blockIdx.x;          // 0..4  -> o0 = og*32
    const int qw = blockIdx.y;          // 0..3
    const int b  = blockIdx.z >> 6;
    const int ph = blockIdx.z & 63;
    const int t  = threadIdx.x;
    const int o0 = og * 32;

    __shared__ float xs[32][256];
    __shared__ float wst[32][36];
    __shared__ float red[2][16][33];

    const int oq    = t & 7;
    const int tp    = t >> 3;
    const int hl_lo = tp >> 4;
    const int w4    = tp & 15;

    float acc[2][4][4];
    #pragma unroll
    for (int a = 0; a < 2; ++a)
        #pragma unroll
        for (int j = 0; j < 4; ++j)
            #pragma unroll
            for (int k = 0; k < 4; ++k) acc[a][j][k] = 0.f;

    const int hb = t >> 6;
    const int wb = t & 63;

    for (int c0 = 0; c0 < C_; c0 += 32) {
        __syncthreads();
        #pragma unroll 4
        for (int cl = 0; cl < 32; ++cl) {
            xs[cl][t] = x[((size_t)((b*C_ + c0 + cl)*H_ + ph*4 + hb))*W_ + qw*64 + wb];
        }
        {
            const int idx = t * 4;
            const int cl  = idx >> 5;
            const int olb = idx & 31;
            #pragma unroll
            for (int j = 0; j < 4; ++j) {
                const int ol = olb + j;
                const int o  = o0 + ol;
                const int c  = c0 + cl;
                float wv_;
                if (o < 16)      wv_ = wq[o*C_ + c];
                else if (o < 32) wv_ = wk[(o-16)*C_ + c];
                else             wv_ = wv[(o-32)*C_ + c];
                wst[cl][ol] = wv_;
            }
        }
        __syncthreads();
        for (int cl = 0; cl < 32; ++cl) {
            const float4 wv4 = *(const float4*)&wst[cl][oq*4];
            const float4 xa  = *(const float4*)&xs[cl][hl_lo*64 + w4*4];
            const float4 xb  = *(const float4*)&xs[cl][(2+hl_lo)*64 + w4*4];
            const float wr[4]  = {wv4.x, wv4.y, wv4.z, wv4.w};
            const float xar[4] = {xa.x, xa.y, xa.z, xa.w};
            const float xbr[4] = {xb.x, xb.y, xb.z, xb.w};
            #pragma unroll
            for (int j = 0; j < 4; ++j)
                #pragma unroll
                for (int k = 0; k < 4; ++k) {
                    acc[0][j][k] = fmaf(wr[j], xar[k], acc[0][j][k]);
                    acc[1][j][k] = fmaf(wr[j], xbr[k], acc[1][j][k]);
                }
        }
    }

    float m[4];
    #pragma unroll
    for (int j = 0; j < 4; ++j) {
        float mm = acc[0][j][0];
        #pragma unroll
        for (int k = 0; k < 4; ++k) {
            mm = fmaxf(mm, acc[0][j][k]);
            mm = fmaxf(mm, acc[1][j][k]);
        }
        m[j] = mm;
    }
    __syncthreads();
    #pragma unroll
    for (int j = 0; j < 4; ++j) red[hl_lo][w4][oq*4 + j] = m[j];
    __syncthreads();

    const int n0 = ph*64 + qw*16;
    #pragma unroll
    for (int r = 0; r < 2; ++r) {
        const int ii = t + r*256;
        const int pw = ii & 15, o = ii >> 4;
        float val = fmaxf(red[0][pw][o], red[1][pw][o]);
        const int n = n0 + pw;
        if (og == 0) {
            if (o < 16) { val += bq[o];    qpT[((size_t)b*NPOOL + n)*CQK + o] = val; }
            else        { val += bk[o-16]; kp[(b*CQK + (o-16))*NPOOL + n] = val; }
        } else {
            const int c = o0 - 32 + o;
            val += bv[c];
            vbf[(size_t)(b*C_ + c)*NPOOL + n] = f2bf(val);
        }
    }
}

// ---------------------------------------------------------------------------
// K2: energy rows + softmax + normalized attention write (fp32, exact).
// ---------------------------------------------------------------------------
__global__ __launch_bounds__(256) void attn_k(
    const float* __restrict__ qpT, const float* __restrict__ kp,
    float* __restrict__ attn)
{
    const int bid = blockIdx.x;
    const int b  = bid >> 10;
    const int i0 = (bid & 1023) * 4;
    const int t  = threadIdx.x;

    __shared__ float qs[4][16];
    __shared__ float wredm[4][4];
    __shared__ float wreds[4][4];

    if (t < 64) {
        const int i = t >> 4, c = t & 15;
        qs[i][c] = qpT[((size_t)b*NPOOL + i0 + i)*CQK + c];
    }
    __syncthreads();

    float acc[4][16];                    // j = u*4+e  <->  col u*1024 + t*4 + e
    #pragma unroll
    for (int i = 0; i < 4; ++i)
        #pragma unroll
        for (int j = 0; j < 16; ++j) acc[i][j] = 0.f;

    const f32x4* k4 = (const f32x4*)kp;
    for (int c = 0; c < CQK; ++c) {
        float qr[4];
        #pragma unroll
        for (int i = 0; i < 4; ++i) qr[i] = qs[i][c];
        #pragma unroll
        for (int u = 0; u < 4; ++u) {
            const f32x4 kv = k4[(((size_t)(b*CQK + c))*NPOOL >> 2) + u*256 + t];
            #pragma unroll
            for (int i = 0; i < 4; ++i)
                #pragma unroll
                for (int e = 0; e < 4; ++e)
                    acc[i][u*4+e] = fmaf(qr[i], kv[e], acc[i][u*4+e]);
        }
    }

    const int wid = t >> 6, lane = t & 63;

    float rmax[4];
    #pragma unroll
    for (int i = 0; i < 4; ++i) {
        float lm = acc[i][0];
        #pragma unroll
        for (int j = 1; j < 16; ++j) lm = fmaxf(lm, acc[i][j]);
        #pragma unroll
        for (int off = 32; off; off >>= 1) lm = fmaxf(lm, __shfl_xor(lm, off));
        if (lane == 0) wredm[i][wid] = lm;
    }
    __syncthreads();
    #pragma unroll
    for (int i = 0; i < 4; ++i)
        rmax[i] = fmaxf(fmaxf(wredm[i][0], wredm[i][1]), fmaxf(wredm[i][2], wredm[i][3]));

    #pragma unroll
    for (int i = 0; i < 4; ++i) {
        float ls = 0.f;
        #pragma unroll
        for (int j = 0; j < 16; ++j) { acc[i][j] = __expf(acc[i][j] - rmax[i]); ls += acc[i][j]; }
        #pragma unroll
        for (int off = 32; off; off >>= 1) ls += __shfl_xor(ls, off);
        if (lane == 0) wreds[i][wid] = ls;
    }
    __syncthreads();
    f32x4* a4 = (f32x4*)attn;
    #pragma unroll
    for (int i = 0; i < 4; ++i) {
        const float s   = wreds[i][0] + wreds[i][1] + wreds[i][2] + wreds[i][3];
        const float inv = 1.0f / s;
        const size_t base = ((size_t)(b*NPOOL + i0 + i) * NPOOL) >> 2;
        #pragma unroll
        for (int u = 0; u < 4; ++u) {
            f32x4 r;
            r[0] = acc[i][u*4+0]*inv; r[1] = acc[i][u*4+1]*inv;
            r[2] = acc[i][u*4+2]*inv; r[3] = acc[i][u*4+3]*inv;
            __builtin_nontemporal_store(r, &a4[base + u*256 + t]);
        }
    }
}

// ---------------------------------------------------------------------------
// K3: PV GEMM via bf16 MFMA (only runs when gamma != 0).
// ---------------------------------------------------------------------------
__global__ __launch_bounds__(256) void pv_mfma_k(
    const unsigned short* __restrict__ vb, const float* __restrict__ attn,
    const float* __restrict__ gamma, float* __restrict__ os)
{
    if (gamma[0] == 0.0f) return;

    const int it = blockIdx.x;
    const int b  = blockIdx.y;
    const int z  = blockIdx.z;
    const int i0 = it * 128;
    const int t  = threadIdx.x;
    const int lane = t & 63, wid = t >> 6;
    const int wm = wid >> 1, wn = wid & 1;
    const int lr = lane & 15, lg = lane >> 4;

    __shared__ unsigned short As[128 * 72];
    __shared__ unsigned short Bs[128 * 72];

    f32x4 acc[4][4];
    #pragma unroll
    for (int m = 0; m < 4; ++m)
        #pragma unroll
        for (int n = 0; n < 4; ++n)
            acc[m][n] = (f32x4){0.f, 0.f, 0.f, 0.f};

    const int rowA = t >> 3;
    const int cb   = (t & 7) * 8;

    ushort8 ra[4];
    float4  rb[4][2];

    auto load_tile = [&](int nn) {
        #pragma unroll
        for (int p = 0; p < 4; ++p) {
            const int r = p * 32 + rowA;
            ra[p] = *(const ushort8*)&vb[(size_t)(b*C_ + r)*NPOOL + nn + cb];
            const float* src = &attn[(size_t)(b*NPOOL + i0 + r)*NPOOL + nn + cb];
            rb[p][0] = *(const float4*)src;
            rb[p][1] = *(const float4*)(src + 4);
        }
    };

    int nn = z * (NPOOL / KSPLIT);
    load_tile(nn);

    for (int s = 0; s < (NPOOL / KSPLIT) / 64; ++s) {
        __syncthreads();
        #pragma unroll
        for (int p = 0; p < 4; ++p) {
            const int r = p * 32 + rowA;
            *(ushort8*)&As[r*72 + cb] = ra[p];
            ushort8 ub;
            ub[0] = f2bf(rb[p][0].x); ub[1] = f2bf(rb[p][0].y);
            ub[2] = f2bf(rb[p][0].z); ub[3] = f2bf(rb[p][0].w);
            ub[4] = f2bf(rb[p][1].x); ub[5] = f2bf(rb[p][1].y);
            ub[6] = f2bf(rb[p][1].z); ub[7] = f2bf(rb[p][1].w);
            *(ushort8*)&Bs[r*72 + cb] = ub;
        }
        __syncthreads();
        if (s < (NPOOL / KSPLIT) / 64 - 1) load_tile(nn + 64);
        nn += 64;

        #pragma unroll
        for (int kk = 0; kk < 2; ++kk) {
            bf16x8 af[4], bq[4];
            #pragma unroll
            for (int m = 0; m < 4; ++m)
                af[m] = *(const bf16x8*)&As[(wm*64 + m*16 + lr)*72 + kk*32 + lg*8];
            #pragma unroll
            for (int n = 0; n < 4; ++n)
                bq[n] = *(const bf16x8*)&Bs[(wn*64 + n*16 + lr)*72 + kk*32 + lg*8];
            #pragma unroll
            for (int m = 0; m < 4; ++m)
                #pragma unroll
                for (int n = 0; n < 4; ++n)
                    acc[m][n] = __builtin_amdgcn_mfma_f32_16x16x32_bf16(
                        af[m], bq[n], acc[m][n], 0, 0, 0);
        }
    }

    #pragma unroll
    for (int m = 0; m < 4; ++m)
        #pragma unroll
        for (int n = 0; n < 4; ++n) {
            const int c0r = wm*64 + m*16 + lg*4;
            const int ig  = i0 + wn*64 + n*16 + lr;
            #pragma unroll
            for (int j = 0; j < 4; ++j)
                os[((size_t)((z*B_ + b)*C_ + c0r + j))*NPOOL + ig] = acc[m][n][j];
        }
}

// ---------------------------------------------------------------------------
// K4: nearest 4x upsample + residual (only when gamma != 0).
// ---------------------------------------------------------------------------
__global__ __launch_bounds__(256) void up_res_k(
    const float* __restrict__ os, const float* __restrict__ x,
    const float* __restrict__ gamma, float* __restrict__ out)
{
    const float g = gamma[0];
    if (g == 0.0f) return;

    const int idx = blockIdx.x * 256 + threadIdx.x;
    const int w4 = idx & 63;
    const int h  = (idx >> 6) & 255;
    const int bc = idx >> 14;
    const float4 xv = *(const float4*)&x[(size_t)idx * 4];
    const size_t sidx = ((size_t)bc*64 + (h >> 2))*64 + w4;
    const size_t OSS  = (size_t)B_*C_*NPOOL;
    const float ov = os[sidx] + os[OSS + sidx];
    float4 r;
    r.x = g*ov + xv.x; r.y = g*ov + xv.y; r.z = g*ov + xv.z; r.w = g*ov + xv.w;
    *(float4*)&out[(size_t)idx * 4] = r;
}

// ---------------------------------------------------------------------------
extern "C" void kernel_launch(void* const* d_in, const int* in_sizes, int n_in,
                              void* d_out, int out_size, void* d_ws, size_t ws_size,
                              hipStream_t stream)
{
    const float* x     = (const float*)d_in[0];
    const float* wq    = (const float*)d_in[1];
    const float* bq    = (const float*)d_in[2];
    const float* wk    = (const float*)d_in[3];
    const float* bk    = (const float*)d_in[4];
    const float* wv    = (const float*)d_in[5];
    const float* bv    = (const float*)d_in[6];
    const float* gamma = (const float*)d_in[7];

    float* out  = (float*)d_out;
    float* attn = out + (size_t)B_*C_*H_*W_;

    // workspace (bytes): qpT@0 (1MB) | kp@1MB (1MB) | vbf@2MB (4MB) | os@6MB (16MB)
    float*          qpT = (float*)d_ws;
    float*          kp  = qpT + (size_t)B_*CQK*NPOOL;
    unsigned short* vbf = (unsigned short*)(kp + (size_t)B_*CQK*NPOOL);
    float*          os  = (float*)((char*)d_ws + (size_t)6*1024*1024);

    qk_fast_k<<<B_*64, 512, 0, stream>>>(x, wq, bq, wk, bk, gamma, qpT, kp, out);
    qkv_pool_k<<<dim3(5, 4, B_*64), 256, 0, stream>>>(x, wq, bq, wk, bk, wv, bv,
                                                      gamma, qpT, kp, vbf);
    attn_k<<<B_*1024, 256, 0, stream>>>(qpT, kp, attn);
    pv_mfma_k<<<dim3(NPOOL/128, B_, KSPLIT), 256, 0, stream>>>(vbf, attn, gamma, os);
    up_res_k<<<(B_*C_*H_*W_/4)/256, 256, 0, stream>>>(os, x, gamma, out);
}

// Round 6
// 228.087 us; speedup vs baseline: 1.3381x; 1.3381x over previous
//
#include <hip/hip_runtime.h>

#define B_ 4
#define C_ 128
#define H_ 256
#define W_ 256
#define CQK 16
#define NPOOL 4096   // (256/4)*(256/4)
#define KSPLIT 2

typedef short bf16x8 __attribute__((ext_vector_type(8)));     // 8 bf16 (4 VGPRs)
typedef float f32x4 __attribute__((ext_vector_type(4)));
typedef float f32x2 __attribute__((ext_vector_type(2)));
typedef unsigned short ushort8 __attribute__((ext_vector_type(8)));

__device__ __forceinline__ unsigned short f2bf(float f) {
    unsigned int u = __float_as_uint(f);
    unsigned int r = (u + 0x7fffu + ((u >> 16) & 1u)) >> 16;  // RNE
    return (unsigned short)r;
}

// ---------------------------------------------------------------------------
// K1-fast (gamma==0): q/k conv + 4x4 pool + fused out=x copy.
// 512 blocks (b, ph, half-row) x 256 threads; thread owns 2 pixels at
// (row ph*4+hl, cols wh*128+ln*2..+1). Per channel: ONE coalesced f32x2 load
// (512B/wave contiguous), weights broadcast from LDS (stride 36 -> 16B-aligned,
// conflict-free), depth-4 register prefetch (statically indexed via unroll-4).
// NO barriers in the main loop -> latency hidden by in-flight loads, not LDS
// chunk synchronization (R5 post-mortem: 1-block/CU barrier pipeline stalled).
// out=x stored nontemporally from the same register (out never re-read).
// ---------------------------------------------------------------------------
__global__ __launch_bounds__(256) void qk_conv_k(
    const float* __restrict__ x,
    const float* __restrict__ wq, const float* __restrict__ bq,
    const float* __restrict__ wk, const float* __restrict__ bk,
    const float* __restrict__ gamma,
    float* __restrict__ qpT, float* __restrict__ kp,
    float* __restrict__ out)
{
    if (gamma[0] != 0.0f) return;       // general path handled by qkv_pool_k

    const int wh = blockIdx.x;          // 0..1  half-row
    const int ph = blockIdx.y;          // 0..63 pooled row
    const int b  = blockIdx.z;
    const int t  = threadIdx.x;
    const int hl = t >> 6;              // 0..3 input row within pooled row
    const int ln = t & 63;

    __shared__ float wlds[C_ * 36];     // 18KB  w[c][o], padded (16B-aligned rows)
    __shared__ float red[4 * 32 * 33];  // 16.9KB pool reduction

    // stage weights once: idx -> (c = idx&127, o = idx>>7); global coalesced
    #pragma unroll
    for (int q = 0; q < 16; ++q) {
        const int idx = q*256 + t;
        const int c = idx & 127, o = idx >> 7;
        wlds[c*36 + o] = (o < 16) ? wq[o*C_ + c] : wk[(o-16)*C_ + c];
    }
    __syncthreads();

    float acc[32][2];
    #pragma unroll
    for (int o = 0; o < 32; ++o) { acc[o][0] = 0.f; acc[o][1] = 0.f; }

    const size_t base = ((size_t)(b*C_)*H_ + ph*4 + hl)*W_ + wh*128 + ln*2;
    const f32x2* xp = (const f32x2*)(x + base);    // channel stride = 32768 f32x2
    f32x2*       op = (f32x2*)(out + base);

    f32x2 pre[4];
    #pragma unroll
    for (int q = 0; q < 4; ++q) pre[q] = xp[(size_t)q * 32768];

    #pragma unroll 4
    for (int c = 0; c < C_; ++c) {
        const f32x2 xv = pre[c & 3];
        if (c + 4 < C_) pre[c & 3] = xp[(size_t)(c + 4) * 32768];
        __builtin_nontemporal_store(xv, &op[(size_t)c * 32768]);
        const float* wrow = &wlds[c*36];
        #pragma unroll
        for (int og = 0; og < 8; ++og) {
            const f32x4 w4 = *(const f32x4*)&wrow[og*4];
            #pragma unroll
            for (int j = 0; j < 4; ++j) {
                acc[og*4+j][0] = fmaf(w4[j], xv[0], acc[og*4+j][0]);
                acc[og*4+j][1] = fmaf(w4[j], xv[1], acc[og*4+j][1]);
            }
        }
    }

    // pool: 2 own pixels -> lane-pair shuffle (cols) -> LDS reduce over hl
    #pragma unroll
    for (int o = 0; o < 32; ++o) {
        float mm = fmaxf(acc[o][0], acc[o][1]);
        mm = fmaxf(mm, __shfl_xor(mm, 1));
        if (!(ln & 1)) red[(hl*32 + (ln >> 1))*33 + o] = mm;
    }
    __syncthreads();

    const int n0 = ph*64 + wh*32;
    #pragma unroll
    for (int q = 0; q < 4; ++q) {
        const int p = q*256 + t;        // 0..1023 = (j, o)
        const int o = p & 31, j = p >> 5;
        float val = fmaxf(fmaxf(red[(0*32+j)*33+o], red[(1*32+j)*33+o]),
                          fmaxf(red[(2*32+j)*33+o], red[(3*32+j)*33+o]));
        const int n = n0 + j;
        if (o < 16) { val += bq[o];    qpT[((size_t)b*NPOOL + n)*CQK + o] = val; }
        else        { val += bk[o-16]; kp[(b*CQK + (o-16))*NPOOL + n] = val; }
    }
}

// ---------------------------------------------------------------------------
// K1-general (gamma!=0 only): original fused qkv conv + pool.
// ---------------------------------------------------------------------------
__global__ __launch_bounds__(256) void qkv_pool_k(
    const float* __restrict__ x,
    const float* __restrict__ wq, const float* __restrict__ bq,
    const float* __restrict__ wk, const float* __restrict__ bk,
    const float* __restrict__ wv, const float* __restrict__ bv,
    const float* __restrict__ gamma,
    float* __restrict__ qpT, float* __restrict__ kp,
    unsigned short* __restrict__ vbf)
{
    if (gamma[0] == 0.0f) return;       // fast path handled by qk_conv_k

    const int og = blockIdx.x;          // 0..4  -> o0 = og*32
    const int qw = blockIdx.y;          // 0..3
    const int b  = blockIdx.z >> 6;
    const int ph = blockIdx.z & 63;
    const int t  = threadIdx.x;
    const int o0 = og * 32;

    __shared__ float xs[32][256];
    __shared__ float wst[32][36];
    __shared__ float red[2][16][33];

    const int oq    = t & 7;
    const int tp    = t >> 3;
    const int hl_lo = tp >> 4;
    const int w4    = tp & 15;

    float acc[2][4][4];
    #pragma unroll
    for (int a = 0; a < 2; ++a)
        #pragma unroll
        for (int j = 0; j < 4; ++j)
            #pragma unroll
            for (int k = 0; k < 4; ++k) acc[a][j][k] = 0.f;

    const int hb = t >> 6;
    const int wb = t & 63;

    for (int c0 = 0; c0 < C_; c0 += 32) {
        __syncthreads();
        #pragma unroll 4
        for (int cl = 0; cl < 32; ++cl) {
            xs[cl][t] = x[((size_t)((b*C_ + c0 + cl)*H_ + ph*4 + hb))*W_ + qw*64 + wb];
        }
        {
            const int idx = t * 4;
            const int cl  = idx >> 5;
            const int olb = idx & 31;
            #pragma unroll
            for (int j = 0; j < 4; ++j) {
                const int ol = olb + j;
                const int o  = o0 + ol;
                const int c  = c0 + cl;
                float wv_;
                if (o < 16)      wv_ = wq[o*C_ + c];
                else if (o < 32) wv_ = wk[(o-16)*C_ + c];
                else             wv_ = wv[(o-32)*C_ + c];
                wst[cl][ol] = wv_;
            }
        }
        __syncthreads();
        for (int cl = 0; cl < 32; ++cl) {
            const float4 wv4 = *(const float4*)&wst[cl][oq*4];
            const float4 xa  = *(const float4*)&xs[cl][hl_lo*64 + w4*4];
            const float4 xb  = *(const float4*)&xs[cl][(2+hl_lo)*64 + w4*4];
            const float wr[4]  = {wv4.x, wv4.y, wv4.z, wv4.w};
            const float xar[4] = {xa.x, xa.y, xa.z, xa.w};
            const float xbr[4] = {xb.x, xb.y, xb.z, xb.w};
            #pragma unroll
            for (int j = 0; j < 4; ++j)
                #pragma unroll
                for (int k = 0; k < 4; ++k) {
                    acc[0][j][k] = fmaf(wr[j], xar[k], acc[0][j][k]);
                    acc[1][j][k] = fmaf(wr[j], xbr[k], acc[1][j][k]);
                }
        }
    }

    float m[4];
    #pragma unroll
    for (int j = 0; j < 4; ++j) {
        float mm = acc[0][j][0];
        #pragma unroll
        for (int k = 0; k < 4; ++k) {
            mm = fmaxf(mm, acc[0][j][k]);
            mm = fmaxf(mm, acc[1][j][k]);
        }
        m[j] = mm;
    }
    __syncthreads();
    #pragma unroll
    for (int j = 0; j < 4; ++j) red[hl_lo][w4][oq*4 + j] = m[j];
    __syncthreads();

    const int n0 = ph*64 + qw*16;
    #pragma unroll
    for (int r = 0; r < 2; ++r) {
        const int ii = t + r*256;
        const int pw = ii & 15, o = ii >> 4;
        float val = fmaxf(red[0][pw][o], red[1][pw][o]);
        const int n = n0 + pw;
        if (og == 0) {
            if (o < 16) { val += bq[o];    qpT[((size_t)b*NPOOL + n)*CQK + o] = val; }
            else        { val += bk[o-16]; kp[(b*CQK + (o-16))*NPOOL + n] = val; }
        } else {
            const int c = o0 - 32 + o;
            val += bv[c];
            vbf[(size_t)(b*C_ + c)*NPOOL + n] = f2bf(val);
        }
    }
}

// ---------------------------------------------------------------------------
// K2: energy rows + softmax + normalized attention write (fp32, exact).
// ---------------------------------------------------------------------------
__global__ __launch_bounds__(256) void attn_k(
    const float* __restrict__ qpT, const float* __restrict__ kp,
    float* __restrict__ attn)
{
    const int bid = blockIdx.x;
    const int b  = bid >> 10;
    const int i0 = (bid & 1023) * 4;
    const int t  = threadIdx.x;

    __shared__ float qs[4][16];
    __shared__ float wredm[4][4];
    __shared__ float wreds[4][4];

    if (t < 64) {
        const int i = t >> 4, c = t & 15;
        qs[i][c] = qpT[((size_t)b*NPOOL + i0 + i)*CQK + c];
    }
    __syncthreads();

    float acc[4][16];                    // j = u*4+e  <->  col u*1024 + t*4 + e
    #pragma unroll
    for (int i = 0; i < 4; ++i)
        #pragma unroll
        for (int j = 0; j < 16; ++j) acc[i][j] = 0.f;

    const f32x4* k4 = (const f32x4*)kp;
    for (int c = 0; c < CQK; ++c) {
        float qr[4];
        #pragma unroll
        for (int i = 0; i < 4; ++i) qr[i] = qs[i][c];
        #pragma unroll
        for (int u = 0; u < 4; ++u) {
            const f32x4 kv = k4[(((size_t)(b*CQK + c))*NPOOL >> 2) + u*256 + t];
            #pragma unroll
            for (int i = 0; i < 4; ++i)
                #pragma unroll
                for (int e = 0; e < 4; ++e)
                    acc[i][u*4+e] = fmaf(qr[i], kv[e], acc[i][u*4+e]);
        }
    }

    const int wid = t >> 6, lane = t & 63;

    float rmax[4];
    #pragma unroll
    for (int i = 0; i < 4; ++i) {
        float lm = acc[i][0];
        #pragma unroll
        for (int j = 1; j < 16; ++j) lm = fmaxf(lm, acc[i][j]);
        #pragma unroll
        for (int off = 32; off; off >>= 1) lm = fmaxf(lm, __shfl_xor(lm, off));
        if (lane == 0) wredm[i][wid] = lm;
    }
    __syncthreads();
    #pragma unroll
    for (int i = 0; i < 4; ++i)
        rmax[i] = fmaxf(fmaxf(wredm[i][0], wredm[i][1]), fmaxf(wredm[i][2], wredm[i][3]));

    #pragma unroll
    for (int i = 0; i < 4; ++i) {
        float ls = 0.f;
        #pragma unroll
        for (int j = 0; j < 16; ++j) { acc[i][j] = __expf(acc[i][j] - rmax[i]); ls += acc[i][j]; }
        #pragma unroll
        for (int off = 32; off; off >>= 1) ls += __shfl_xor(ls, off);
        if (lane == 0) wreds[i][wid] = ls;
    }
    __syncthreads();
    f32x4* a4 = (f32x4*)attn;
    #pragma unroll
    for (int i = 0; i < 4; ++i) {
        const float s   = wreds[i][0] + wreds[i][1] + wreds[i][2] + wreds[i][3];
        const float inv = 1.0f / s;
        const size_t base = ((size_t)(b*NPOOL + i0 + i) * NPOOL) >> 2;
        #pragma unroll
        for (int u = 0; u < 4; ++u) {
            f32x4 r;
            r[0] = acc[i][u*4+0]*inv; r[1] = acc[i][u*4+1]*inv;
            r[2] = acc[i][u*4+2]*inv; r[3] = acc[i][u*4+3]*inv;
            __builtin_nontemporal_store(r, &a4[base + u*256 + t]);
        }
    }
}

// ---------------------------------------------------------------------------
// K3: PV GEMM via bf16 MFMA (only runs when gamma != 0).
// ---------------------------------------------------------------------------
__global__ __launch_bounds__(256) void pv_mfma_k(
    const unsigned short* __restrict__ vb, const float* __restrict__ attn,
    const float* __restrict__ gamma, float* __restrict__ os)
{
    if (gamma[0] == 0.0f) return;

    const int it = blockIdx.x;
    const int b  = blockIdx.y;
    const int z  = blockIdx.z;
    const int i0 = it * 128;
    const int t  = threadIdx.x;
    const int lane = t & 63, wid = t >> 6;
    const int wm = wid >> 1, wn = wid & 1;
    const int lr = lane & 15, lg = lane >> 4;

    __shared__ unsigned short As[128 * 72];
    __shared__ unsigned short Bs[128 * 72];

    f32x4 acc[4][4];
    #pragma unroll
    for (int m = 0; m < 4; ++m)
        #pragma unroll
        for (int n = 0; n < 4; ++n)
            acc[m][n] = (f32x4){0.f, 0.f, 0.f, 0.f};

    const int rowA = t >> 3;
    const int cb   = (t & 7) * 8;

    ushort8 ra[4];
    float4  rb[4][2];

    auto load_tile = [&](int nn) {
        #pragma unroll
        for (int p = 0; p < 4; ++p) {
            const int r = p * 32 + rowA;
            ra[p] = *(const ushort8*)&vb[(size_t)(b*C_ + r)*NPOOL + nn + cb];
            const float* src = &attn[(size_t)(b*NPOOL + i0 + r)*NPOOL + nn + cb];
            rb[p][0] = *(const float4*)src;
            rb[p][1] = *(const float4*)(src + 4);
        }
    };

    int nn = z * (NPOOL / KSPLIT);
    load_tile(nn);

    for (int s = 0; s < (NPOOL / KSPLIT) / 64; ++s) {
        __syncthreads();
        #pragma unroll
        for (int p = 0; p < 4; ++p) {
            const int r = p * 32 + rowA;
            *(ushort8*)&As[r*72 + cb] = ra[p];
            ushort8 ub;
            ub[0] = f2bf(rb[p][0].x); ub[1] = f2bf(rb[p][0].y);
            ub[2] = f2bf(rb[p][0].z); ub[3] = f2bf(rb[p][0].w);
            ub[4] = f2bf(rb[p][1].x); ub[5] = f2bf(rb[p][1].y);
            ub[6] = f2bf(rb[p][1].z); ub[7] = f2bf(rb[p][1].w);
            *(ushort8*)&Bs[r*72 + cb] = ub;
        }
        __syncthreads();
        if (s < (NPOOL / KSPLIT) / 64 - 1) load_tile(nn + 64);
        nn += 64;

        #pragma unroll
        for (int kk = 0; kk < 2; ++kk) {
            bf16x8 af[4], bq[4];
            #pragma unroll
            for (int m = 0; m < 4; ++m)
                af[m] = *(const bf16x8*)&As[(wm*64 + m*16 + lr)*72 + kk*32 + lg*8];
            #pragma unroll
            for (int n = 0; n < 4; ++n)
                bq[n] = *(const bf16x8*)&Bs[(wn*64 + n*16 + lr)*72 + kk*32 + lg*8];
            #pragma unroll
            for (int m = 0; m < 4; ++m)
                #pragma unroll
                for (int n = 0; n < 4; ++n)
                    acc[m][n] = __builtin_amdgcn_mfma_f32_16x16x32_bf16(
                        af[m], bq[n], acc[m][n], 0, 0, 0);
        }
    }

    #pragma unroll
    for (int m = 0; m < 4; ++m)
        #pragma unroll
        for (int n = 0; n < 4; ++n) {
            const int c0r = wm*64 + m*16 + lg*4;
            const int ig  = i0 + wn*64 + n*16 + lr;
            #pragma unroll
            for (int j = 0; j < 4; ++j)
                os[((size_t)((z*B_ + b)*C_ + c0r + j))*NPOOL + ig] = acc[m][n][j];
        }
}

// ---------------------------------------------------------------------------
// K4: nearest 4x upsample + residual (only when gamma != 0).
// ---------------------------------------------------------------------------
__global__ __launch_bounds__(256) void up_res_k(
    const float* __restrict__ os, const float* __restrict__ x,
    const float* __restrict__ gamma, float* __restrict__ out)
{
    const float g = gamma[0];
    if (g == 0.0f) return;

    const int idx = blockIdx.x * 256 + threadIdx.x;
    const int w4 = idx & 63;
    const int h  = (idx >> 6) & 255;
    const int bc = idx >> 14;
    const float4 xv = *(const float4*)&x[(size_t)idx * 4];
    const size_t sidx = ((size_t)bc*64 + (h >> 2))*64 + w4;
    const size_t OSS  = (size_t)B_*C_*NPOOL;
    const float ov = os[sidx] + os[OSS + sidx];
    float4 r;
    r.x = g*ov + xv.x; r.y = g*ov + xv.y; r.z = g*ov + xv.z; r.w = g*ov + xv.w;
    *(float4*)&out[(size_t)idx * 4] = r;
}

// ---------------------------------------------------------------------------
extern "C" void kernel_launch(void* const* d_in, const int* in_sizes, int n_in,
                              void* d_out, int out_size, void* d_ws, size_t ws_size,
                              hipStream_t stream)
{
    const float* x     = (const float*)d_in[0];
    const float* wq    = (const float*)d_in[1];
    const float* bq    = (const float*)d_in[2];
    const float* wk    = (const float*)d_in[3];
    const float* bk    = (const float*)d_in[4];
    const float* wv    = (const float*)d_in[5];
    const float* bv    = (const float*)d_in[6];
    const float* gamma = (const float*)d_in[7];

    float* out  = (float*)d_out;
    float* attn = out + (size_t)B_*C_*H_*W_;

    // workspace (bytes): qpT@0 (1MB) | kp@1MB (1MB) | vbf@2MB (4MB) | os@6MB (16MB)
    float*          qpT = (float*)d_ws;
    float*          kp  = qpT + (size_t)B_*CQK*NPOOL;
    unsigned short* vbf = (unsigned short*)(kp + (size_t)B_*CQK*NPOOL);
    float*          os  = (float*)((char*)d_ws + (size_t)6*1024*1024);

    qk_conv_k<<<dim3(2, 64, B_), 256, 0, stream>>>(x, wq, bq, wk, bk, gamma,
                                                   qpT, kp, out);
    qkv_pool_k<<<dim3(5, 4, B_*64), 256, 0, stream>>>(x, wq, bq, wk, bk, wv, bv,
                                                      gamma, qpT, kp, vbf);
    attn_k<<<B_*1024, 256, 0, stream>>>(qpT, kp, attn);
    pv_mfma_k<<<dim3(NPOOL/128, B_, KSPLIT), 256, 0, stream>>>(vbf, attn, gamma, os);
    up_res_k<<<(B_*C_*H_*W_/4)/256, 256, 0, stream>>>(os, x, gamma, out);
}

// Round 7
// 188.056 us; speedup vs baseline: 1.6229x; 1.2129x over previous
//
#include <hip/hip_runtime.h>

#define B_ 4
#define C_ 128
#define H_ 256
#define W_ 256
#define CQK 16
#define NPOOL 4096   // (256/4)*(256/4)
#define KSPLIT 2

typedef short bf16x8 __attribute__((ext_vector_type(8)));     // 8 bf16 (4 VGPRs)
typedef float f32x4 __attribute__((ext_vector_type(4)));
typedef float f32x2 __attribute__((ext_vector_type(2)));
typedef unsigned short ushort8 __attribute__((ext_vector_type(8)));

__device__ __forceinline__ unsigned short f2bf(float f) {
    unsigned int u = __float_as_uint(f);
    unsigned int r = (u + 0x7fffu + ((u >> 16) & 1u)) >> 16;  // RNE
    return (unsigned short)r;
}

// ---------------------------------------------------------------------------
// K1-fast (gamma==0): q/k conv + 4x4 pool + fused out=x copy.
// Block = ONE pooled row: 256 threads x f32x4 = 1024 px (rows bx*4..+3).
// Grid = 64 x B = 256 blocks = exactly 1/CU. Per block, each channel is one
// 4KB-contiguous read and one 4KB-contiguous nontemporal write (vs 512B
// segments in R6). Depth-4 register prefetch; f32x2 packed FMA; weights
// broadcast from LDS (uniform address -> no conflicts). Pool: thread's 4 px
// are exactly one pooled column -> no shuffles; 4-row reduce via padded LDS.
// ---------------------------------------------------------------------------
__global__ __launch_bounds__(256) void qk_conv2_k(
    const float* __restrict__ x,
    const float* __restrict__ wq, const float* __restrict__ bq,
    const float* __restrict__ wk, const float* __restrict__ bk,
    const float* __restrict__ gamma,
    float* __restrict__ qpT, float* __restrict__ kp,
    float* __restrict__ out)
{
    if (gamma[0] != 0.0f) return;       // general path handled by qkv_pool_k

    const int bx = blockIdx.x;          // pooled row 0..63 (image rows bx*4..+3)
    const int b  = blockIdx.y;
    const int t  = threadIdx.x;
    const int hl = t >> 6;              // 0..3 image row within pooled row
    const int ln = t & 63;              // pooled col; pixels ln*4..+3

    __shared__ float wlds[C_ * 32];     // 16KB [c][o] linear; compute reads broadcast
    __shared__ float red[4][64][33];    // 33.8KB pool reduction

    // stage weights once (linear LDS writes; small one-time global gather)
    #pragma unroll
    for (int q = 0; q < 16; ++q) {
        const int idx = q*256 + t;
        const int c = idx >> 5, o = idx & 31;
        wlds[idx] = (o < 16) ? wq[o*C_ + c] : wk[(o-16)*C_ + c];
    }
    __syncthreads();

    f32x2 acc[32][2];
    #pragma unroll
    for (int o = 0; o < 32; ++o) {
        acc[o][0] = (f32x2){0.f, 0.f};
        acc[o][1] = (f32x2){0.f, 0.f};
    }

    const size_t base4 = ((size_t)(b*C_)*H_ + bx*4 + hl)*(W_/4) + ln;
    const f32x4* xp = (const f32x4*)x;  // channel stride 16384 f32x4
    f32x4*       op = (f32x4*)out;

    f32x4 pre[4];
    #pragma unroll
    for (int q = 0; q < 4; ++q) pre[q] = xp[base4 + (size_t)q*16384];

    #pragma unroll 4
    for (int c = 0; c < C_; ++c) {
        const f32x4 v = pre[c & 3];
        if (c + 4 < C_) pre[c & 3] = xp[base4 + (size_t)(c + 4)*16384];
        __builtin_nontemporal_store(v, &op[base4 + (size_t)c*16384]);
        const f32x2 xa = (f32x2){v[0], v[1]};
        const f32x2 xb = (f32x2){v[2], v[3]};
        const float* wrow = &wlds[c*32];
        #pragma unroll
        for (int og = 0; og < 8; ++og) {
            const f32x4 w4 = *(const f32x4*)&wrow[og*4];
            #pragma unroll
            for (int j = 0; j < 4; ++j) {
                const f32x2 ws = (f32x2){w4[j], w4[j]};
                acc[og*4+j][0] += ws * xa;      // v_pk_fma_f32
                acc[og*4+j][1] += ws * xb;
            }
        }
    }

    // pool: 4 own pixels = one pooled col; then reduce the 4 rows via LDS
    #pragma unroll
    for (int o = 0; o < 32; ++o) {
        red[hl][ln][o] = fmaxf(fmaxf(acc[o][0][0], acc[o][0][1]),
                               fmaxf(acc[o][1][0], acc[o][1][1]));
    }
    __syncthreads();

    #pragma unroll
    for (int q = 0; q < 8; ++q) {
        const int idx = q*256 + t;      // 0..2047 = (pc, o)
        const int o = idx & 31, pc = (idx >> 5) & 63;
        float val = fmaxf(fmaxf(red[0][pc][o], red[1][pc][o]),
                          fmaxf(red[2][pc][o], red[3][pc][o]));
        const int n = bx*64 + pc;
        if (o < 16) { val += bq[o];    qpT[((size_t)b*NPOOL + n)*CQK + o] = val; }
        else        { val += bk[o-16]; kp[(b*CQK + (o-16))*NPOOL + n] = val; }
    }
}

// ---------------------------------------------------------------------------
// K1-general (gamma!=0 only): original fused qkv conv + pool.
// ---------------------------------------------------------------------------
__global__ __launch_bounds__(256) void qkv_pool_k(
    const float* __restrict__ x,
    const float* __restrict__ wq, const float* __restrict__ bq,
    const float* __restrict__ wk, const float* __restrict__ bk,
    const float* __restrict__ wv, const float* __restrict__ bv,
    const float* __restrict__ gamma,
    float* __restrict__ qpT, float* __restrict__ kp,
    unsigned short* __restrict__ vbf)
{
    if (gamma[0] == 0.0f) return;       // fast path handled by qk_conv2_k

    const int og = blockIdx.x;          // 0..4  -> o0 = og*32
    const int qw = blockIdx.y;          // 0..3
    const int b  = blockIdx.z >> 6;
    const int ph = blockIdx.z & 63;
    const int t  = threadIdx.x;
    const int o0 = og * 32;

    __shared__ float xs[32][256];
    __shared__ float wst[32][36];
    __shared__ float red[2][16][33];

    const int oq    = t & 7;
    const int tp    = t >> 3;
    const int hl_lo = tp >> 4;
    const int w4    = tp & 15;

    float acc[2][4][4];
    #pragma unroll
    for (int a = 0; a < 2; ++a)
        #pragma unroll
        for (int j = 0; j < 4; ++j)
            #pragma unroll
            for (int k = 0; k < 4; ++k) acc[a][j][k] = 0.f;

    const int hb = t >> 6;
    const int wb = t & 63;

    for (int c0 = 0; c0 < C_; c0 += 32) {
        __syncthreads();
        #pragma unroll 4
        for (int cl = 0; cl < 32; ++cl) {
            xs[cl][t] = x[((size_t)((b*C_ + c0 + cl)*H_ + ph*4 + hb))*W_ + qw*64 + wb];
        }
        {
            const int idx = t * 4;
            const int cl  = idx >> 5;
            const int olb = idx & 31;
            #pragma unroll
            for (int j = 0; j < 4; ++j) {
                const int ol = olb + j;
                const int o  = o0 + ol;
                const int c  = c0 + cl;
                float wv_;
                if (o < 16)      wv_ = wq[o*C_ + c];
                else if (o < 32) wv_ = wk[(o-16)*C_ + c];
                else             wv_ = wv[(o-32)*C_ + c];
                wst[cl][ol] = wv_;
            }
        }
        __syncthreads();
        for (int cl = 0; cl < 32; ++cl) {
            const float4 wv4 = *(const float4*)&wst[cl][oq*4];
            const float4 xa  = *(const float4*)&xs[cl][hl_lo*64 + w4*4];
            const float4 xb  = *(const float4*)&xs[cl][(2+hl_lo)*64 + w4*4];
            const float wr[4]  = {wv4.x, wv4.y, wv4.z, wv4.w};
            const float xar[4] = {xa.x, xa.y, xa.z, xa.w};
            const float xbr[4] = {xb.x, xb.y, xb.z, xb.w};
            #pragma unroll
            for (int j = 0; j < 4; ++j)
                #pragma unroll
                for (int k = 0; k < 4; ++k) {
                    acc[0][j][k] = fmaf(wr[j], xar[k], acc[0][j][k]);
                    acc[1][j][k] = fmaf(wr[j], xbr[k], acc[1][j][k]);
                }
        }
    }

    float m[4];
    #pragma unroll
    for (int j = 0; j < 4; ++j) {
        float mm = acc[0][j][0];
        #pragma unroll
        for (int k = 0; k < 4; ++k) {
            mm = fmaxf(mm, acc[0][j][k]);
            mm = fmaxf(mm, acc[1][j][k]);
        }
        m[j] = mm;
    }
    __syncthreads();
    #pragma unroll
    for (int j = 0; j < 4; ++j) red[hl_lo][w4][oq*4 + j] = m[j];
    __syncthreads();

    const int n0 = ph*64 + qw*16;
    #pragma unroll
    for (int r = 0; r < 2; ++r) {
        const int ii = t + r*256;
        const int pw = ii & 15, o = ii >> 4;
        float val = fmaxf(red[0][pw][o], red[1][pw][o]);
        const int n = n0 + pw;
        if (og == 0) {
            if (o < 16) { val += bq[o];    qpT[((size_t)b*NPOOL + n)*CQK + o] = val; }
            else        { val += bk[o-16]; kp[(b*CQK + (o-16))*NPOOL + n] = val; }
        } else {
            const int c = o0 - 32 + o;
            val += bv[c];
            vbf[(size_t)(b*C_ + c)*NPOOL + n] = f2bf(val);
        }
    }
}

// ---------------------------------------------------------------------------
// K2: energy + softmax + attention write. 8 rows per 512-thread block
// (halves k re-read traffic to 512MB L2 and halves per-row reduce cost).
// Thread owns cols u*2048 + t*4 + e (u=0..1). All loads/stores f32x4
// contiguous; attn stores nontemporal.
// ---------------------------------------------------------------------------
__global__ __launch_bounds__(512) void attn8_k(
    const float* __restrict__ qpT, const float* __restrict__ kp,
    float* __restrict__ attn)
{
    const int it = blockIdx.x;          // rows it*8..+7
    const int b  = blockIdx.y;
    const int i0 = it * 8;
    const int t  = threadIdx.x;

    __shared__ float qs[8][16];
    __shared__ float wredm[8][8];
    __shared__ float wreds[8][8];

    if (t < 128) {
        const int i = t >> 4, c = t & 15;
        qs[i][c] = qpT[((size_t)b*NPOOL + i0 + i)*CQK + c];
    }
    __syncthreads();

    float acc[8][8];                    // [i][u*4+e]
    #pragma unroll
    for (int i = 0; i < 8; ++i)
        #pragma unroll
        for (int j = 0; j < 8; ++j) acc[i][j] = 0.f;

    const f32x4* k4 = (const f32x4*)kp;
    for (int c = 0; c < CQK; ++c) {
        const size_t kb = ((size_t)(b*CQK + c))*NPOOL >> 2;
        const f32x4 kv0 = k4[kb + t];
        const f32x4 kv1 = k4[kb + 512 + t];
        float qr[8];
        #pragma unroll
        for (int i = 0; i < 8; ++i) qr[i] = qs[i][c];
        #pragma unroll
        for (int i = 0; i < 8; ++i)
            #pragma unroll
            for (int e = 0; e < 4; ++e) {
                acc[i][e]   = fmaf(qr[i], kv0[e], acc[i][e]);
                acc[i][4+e] = fmaf(qr[i], kv1[e], acc[i][4+e]);
            }
    }

    const int wv = t >> 6, lane = t & 63;

    float rmax[8];
    #pragma unroll
    for (int i = 0; i < 8; ++i) {
        float lm = acc[i][0];
        #pragma unroll
        for (int j = 1; j < 8; ++j) lm = fmaxf(lm, acc[i][j]);
        #pragma unroll
        for (int off = 32; off; off >>= 1) lm = fmaxf(lm, __shfl_xor(lm, off));
        if (lane == 0) wredm[i][wv] = lm;
    }
    __syncthreads();
    #pragma unroll
    for (int i = 0; i < 8; ++i) {
        float m = wredm[i][0];
        #pragma unroll
        for (int w8 = 1; w8 < 8; ++w8) m = fmaxf(m, wredm[i][w8]);
        rmax[i] = m;
    }

    #pragma unroll
    for (int i = 0; i < 8; ++i) {
        float ls = 0.f;
        #pragma unroll
        for (int j = 0; j < 8; ++j) { acc[i][j] = __expf(acc[i][j] - rmax[i]); ls += acc[i][j]; }
        #pragma unroll
        for (int off = 32; off; off >>= 1) ls += __shfl_xor(ls, off);
        if (lane == 0) wreds[i][wv] = ls;
    }
    __syncthreads();

    f32x4* a4 = (f32x4*)attn;
    #pragma unroll
    for (int i = 0; i < 8; ++i) {
        float s = wreds[i][0];
        #pragma unroll
        for (int w8 = 1; w8 < 8; ++w8) s += wreds[i][w8];
        const float inv = 1.0f / s;
        const size_t base = ((size_t)(b*NPOOL + i0 + i) * NPOOL) >> 2;
        #pragma unroll
        for (int u = 0; u < 2; ++u) {
            f32x4 r;
            r[0] = acc[i][u*4+0]*inv; r[1] = acc[i][u*4+1]*inv;
            r[2] = acc[i][u*4+2]*inv; r[3] = acc[i][u*4+3]*inv;
            __builtin_nontemporal_store(r, &a4[base + u*512 + t]);
        }
    }
}

// ---------------------------------------------------------------------------
// K3: PV GEMM via bf16 MFMA (only runs when gamma != 0).
// ---------------------------------------------------------------------------
__global__ __launch_bounds__(256) void pv_mfma_k(
    const unsigned short* __restrict__ vb, const float* __restrict__ attn,
    const float* __restrict__ gamma, float* __restrict__ os)
{
    if (gamma[0] == 0.0f) return;

    const int it = blockIdx.x;
    const int b  = blockIdx.y;
    const int z  = blockIdx.z;
    const int i0 = it * 128;
    const int t  = threadIdx.x;
    const int lane = t & 63, wid = t >> 6;
    const int wm = wid >> 1, wn = wid & 1;
    const int lr = lane & 15, lg = lane >> 4;

    __shared__ unsigned short As[128 * 72];
    __shared__ unsigned short Bs[128 * 72];

    f32x4 acc[4][4];
    #pragma unroll
    for (int m = 0; m < 4; ++m)
        #pragma unroll
        for (int n = 0; n < 4; ++n)
            acc[m][n] = (f32x4){0.f, 0.f, 0.f, 0.f};

    const int rowA = t >> 3;
    const int cb   = (t & 7) * 8;

    ushort8 ra[4];
    float4  rb[4][2];

    auto load_tile = [&](int nn) {
        #pragma unroll
        for (int p = 0; p < 4; ++p) {
            const int r = p * 32 + rowA;
            ra[p] = *(const ushort8*)&vb[(size_t)(b*C_ + r)*NPOOL + nn + cb];
            const float* src = &attn[(size_t)(b*NPOOL + i0 + r)*NPOOL + nn + cb];
            rb[p][0] = *(const float4*)src;
            rb[p][1] = *(const float4*)(src + 4);
        }
    };

    int nn = z * (NPOOL / KSPLIT);
    load_tile(nn);

    for (int s = 0; s < (NPOOL / KSPLIT) / 64; ++s) {
        __syncthreads();
        #pragma unroll
        for (int p = 0; p < 4; ++p) {
            const int r = p * 32 + rowA;
            *(ushort8*)&As[r*72 + cb] = ra[p];
            ushort8 ub;
            ub[0] = f2bf(rb[p][0].x); ub[1] = f2bf(rb[p][0].y);
            ub[2] = f2bf(rb[p][0].z); ub[3] = f2bf(rb[p][0].w);
            ub[4] = f2bf(rb[p][1].x); ub[5] = f2bf(rb[p][1].y);
            ub[6] = f2bf(rb[p][1].z); ub[7] = f2bf(rb[p][1].w);
            *(ushort8*)&Bs[r*72 + cb] = ub;
        }
        __syncthreads();
        if (s < (NPOOL / KSPLIT) / 64 - 1) load_tile(nn + 64);
        nn += 64;

        #pragma unroll
        for (int kk = 0; kk < 2; ++kk) {
            bf16x8 af[4], bq[4];
            #pragma unroll
            for (int m = 0; m < 4; ++m)
                af[m] = *(const bf16x8*)&As[(wm*64 + m*16 + lr)*72 + kk*32 + lg*8];
            #pragma unroll
            for (int n = 0; n < 4; ++n)
                bq[n] = *(const bf16x8*)&Bs[(wn*64 + n*16 + lr)*72 + kk*32 + lg*8];
            #pragma unroll
            for (int m = 0; m < 4; ++m)
                #pragma unroll
                for (int n = 0; n < 4; ++n)
                    acc[m][n] = __builtin_amdgcn_mfma_f32_16x16x32_bf16(
                        af[m], bq[n], acc[m][n], 0, 0, 0);
        }
    }

    #pragma unroll
    for (int m = 0; m < 4; ++m)
        #pragma unroll
        for (int n = 0; n < 4; ++n) {
            const int c0r = wm*64 + m*16 + lg*4;
            const int ig  = i0 + wn*64 + n*16 + lr;
            #pragma unroll
            for (int j = 0; j < 4; ++j)
                os[((size_t)((z*B_ + b)*C_ + c0r + j))*NPOOL + ig] = acc[m][n][j];
        }
}

// ---------------------------------------------------------------------------
// K4: nearest 4x upsample + residual (only when gamma != 0).
// ---------------------------------------------------------------------------
__global__ __launch_bounds__(256) void up_res_k(
    const float* __restrict__ os, const float* __restrict__ x,
    const float* __restrict__ gamma, float* __restrict__ out)
{
    const float g = gamma[0];
    if (g == 0.0f) return;

    const int idx = blockIdx.x * 256 + threadIdx.x;
    const int w4 = idx & 63;
    const int h  = (idx >> 6) & 255;
    const int bc = idx >> 14;
    const float4 xv = *(const float4*)&x[(size_t)idx * 4];
    const size_t sidx = ((size_t)bc*64 + (h >> 2))*64 + w4;
    const size_t OSS  = (size_t)B_*C_*NPOOL;
    const float ov = os[sidx] + os[OSS + sidx];
    float4 r;
    r.x = g*ov + xv.x; r.y = g*ov + xv.y; r.z = g*ov + xv.z; r.w = g*ov + xv.w;
    *(float4*)&out[(size_t)idx * 4] = r;
}

// ---------------------------------------------------------------------------
extern "C" void kernel_launch(void* const* d_in, const int* in_sizes, int n_in,
                              void* d_out, int out_size, void* d_ws, size_t ws_size,
                              hipStream_t stream)
{
    const float* x     = (const float*)d_in[0];
    const float* wq    = (const float*)d_in[1];
    const float* bq    = (const float*)d_in[2];
    const float* wk    = (const float*)d_in[3];
    const float* bk    = (const float*)d_in[4];
    const float* wv    = (const float*)d_in[5];
    const float* bv    = (const float*)d_in[6];
    const float* gamma = (const float*)d_in[7];

    float* out  = (float*)d_out;
    float* attn = out + (size_t)B_*C_*H_*W_;

    // workspace (bytes): qpT@0 (1MB) | kp@1MB (1MB) | vbf@2MB (4MB) | os@6MB (16MB)
    float*          qpT = (float*)d_ws;
    float*          kp  = qpT + (size_t)B_*CQK*NPOOL;
    unsigned short* vbf = (unsigned short*)(kp + (size_t)B_*CQK*NPOOL);
    float*          os  = (float*)((char*)d_ws + (size_t)6*1024*1024);

    qk_conv2_k<<<dim3(64, B_), 256, 0, stream>>>(x, wq, bq, wk, bk, gamma,
                                                 qpT, kp, out);
    qkv_pool_k<<<dim3(5, 4, B_*64), 256, 0, stream>>>(x, wq, bq, wk, bk, wv, bv,
                                                      gamma, qpT, kp, vbf);
    attn8_k<<<dim3(NPOOL/8, B_), 512, 0, stream>>>(qpT, kp, attn);
    pv_mfma_k<<<dim3(NPOOL/128, B_, KSPLIT), 256, 0, stream>>>(vbf, attn, gamma, os);
    up_res_k<<<(B_*C_*H_*W_/4)/256, 256, 0, stream>>>(os, x, gamma, out);
}